// Round 9
// baseline (1351.707 us; speedup 1.0000x reference)
//
#include <hip/hip_runtime.h>
#include <hip/hip_bf16.h>

// Problem constants (from reference): B=64, NCLS=200 -> BN rows = 12800
#define BROWS  12800
#define TSTEPS 8
#define EMB    300
#define EMBP   320          // EMB padded to /32, x-slot width
#define RNN    512
#define NG     2048         // 4*RNN gate width
#define K1     832          // EMBP + RNN  (layer-1 concat GEMM K), 13*64
#define K2     1024         // RNN + RNN   (layer-2 concat GEMM K), 16*64
#define VOCAB  20000

typedef short bf16x8 __attribute__((ext_vector_type(8)));   // 8 bf16 in 4 VGPRs (m89-verified operand type)
typedef float f32x4  __attribute__((ext_vector_type(4)));
typedef __hip_bfloat16 bf16;

__device__ __forceinline__ float sigmoidf_(float x) { return 1.f / (1.f + __expf(-x)); }
// exp-based tanh: exact saturation at +-inf, ~ulp-level error vs tanhf, one v_exp
__device__ __forceinline__ float tanhf_(float x)    { return 1.f - 2.f / (__expf(2.f * x) + 1.f); }

// async global->LDS, 16B/lane, offset arg ALWAYS 0.
// ROUND-7 LESSON (correctness failure, absmax 0.30): a NON-ZERO offset arg
// to __builtin_amdgcn_global_load_lds scrambles the staged tiles on gfx950.
// K-advance must be expressed on the POINTER (compile-time literal).
#define GL16(p, l)                                                          \
    __builtin_amdgcn_global_load_lds(                                       \
        (const __attribute__((address_space(1))) void*)(p),                 \
        (__attribute__((address_space(3))) void*)(l), 16, 0, 0)

// ---------------------------------------------------------------------------
// Weight repack (round-3 proven): fp32 -> bf16, K-concat LINEAR row-major
// [N=2048][K], GATE-INTERLEAVED row permutation: output row n encodes
//   w = n&15 (unit), g = (n>>4)&3 (gate i,f,g,o), b = n>>6 (unit group)
//   original row = g*512 + b*16 + w
// => each wave's 64-col span = [i|f|g|o] of the same 16 units (epilogue needs
// no cross-lane exchange). Emits permuted combined biases Bp = bih+bhh.
// ---------------------------------------------------------------------------
__global__ void convert_weights(const float* __restrict__ Wih1, const float* __restrict__ Whh1,
                                const float* __restrict__ Wih2, const float* __restrict__ Whh2,
                                const float* __restrict__ bih1, const float* __restrict__ bhh1,
                                const float* __restrict__ bih2, const float* __restrict__ bhh2,
                                bf16* __restrict__ Wc1, bf16* __restrict__ Wc2,
                                float* __restrict__ Bp1, float* __restrict__ Bp2) {
    int idx = blockIdx.x * 256 + threadIdx.x;
    const int n1 = NG * K1;   // 1,703,936
    const int n2 = NG * K2;   // 2,097,152
    if (idx < n1) {
        int n = idx / K1, k = idx - n * K1;
        int on = ((n >> 4) & 3) * RNN + (n >> 6) * 16 + (n & 15);
        float v = 0.f;
        if (k < EMB)        v = Wih1[on * EMB + k];
        else if (k >= EMBP) v = Whh1[on * RNN + (k - EMBP)];
        Wc1[idx] = __float2bfloat16(v);
    }
    if (idx < n2) {
        int n = idx >> 10, k = idx & (K2 - 1);
        int on = ((n >> 4) & 3) * RNN + (n >> 6) * 16 + (n & 15);
        float v = (k < RNN) ? Wih2[on * RNN + k] : Whh2[on * RNN + (k - RNN)];
        Wc2[idx] = __float2bfloat16(v);
    }
    if (idx < NG) {
        int on = ((idx >> 4) & 3) * RNN + (idx >> 6) * 16 + (idx & 15);
        Bp1[idx] = bih1[on] + bhh1[on];
        Bp2[idx] = bih2[on] + bhh2[on];
    }
}

// ---------------------------------------------------------------------------
// One-time tanh(word2vec) table, bf16 [VOCAB][320] (cols 300..319 zero).
// ---------------------------------------------------------------------------
__global__ void tanh_w2v(const float* __restrict__ w2v, bf16* __restrict__ W2Vt) {
    int row = blockIdx.x;
    int col = threadIdx.x;                 // 0..319
    float v = (col < EMB) ? tanhf_(w2v[row * EMB + col]) : 0.f;
    W2Vt[(size_t)row * EMBP + col] = __float2bfloat16(v);
}

// ---------------------------------------------------------------------------
// ROUND-16: 256x256 tile, 16-wave (1024-thr), SAME simple 2-barrier schedule.
//
// WHY (rounds 5-8 evidence): merged dispatch pinned at 122.5us across FETCH
// 219->125MB and VALU 54->45% — time tracks ONLY staged bytes / ~12 TB/s
// (r4-L1 10.2, r4-L2 11.5, merged 12.1 TB/s staging rate = the per-CU
// vector-memory return ceiling, ~20 B/cyc/CU; global_load_lds gets no L1
// reuse). Staged bytes ∝ (1/BM+1/BN): 256^2 halves them (1.48GB->743MB).
// Prior 256^2 failures (rounds 8-10 of session 1) were 8-wave = 2 waves/SIMD
// lockstep deep pipelines; THIS kernel keeps 4 waves/SIMD (16 waves, one
// block/CU) and the verified stage->bar->compute->bar structure, so SIMD-
// level overlap is preserved. Per-thread register shape is IDENTICAL to the
// verified 128^2 kernel: wave tile 64x64, acc[4][4]=64 AGPR + ~64 VGPR = 128
// = exactly 4 waves/SIMD. LDS 64KB single-buffered (sA 32K + sB 32K).
// Floors: staging 62us, LDS-read 48us, MFMA 12us per merged dispatch.
//
// All proven sub-structures preserved: XOR chunk swizzle (zero conflicts),
// gate-interleaved W, W2Vt x-gather, role-merged dispatches, XCD chunking,
// czero, full unroll with literal offsets, fused LSTM epilogue with LDS
// h-transpose. ROUND-7 LESSON: builtin offset arg stays 0.
// ---------------------------------------------------------------------------
#define BM 256
#define BN 256

// 4 staging loads for one K-tile (1024 thr): A 2 chunks + W 2 chunks,
// literal element offsets AE/WE (array indices literal -> registers)
#define STAGE4(AP, AE, WE) do {                                             \
    GL16(AP[0] + (AE), &sA[(0 * 1024 + tid) * 8]);                          \
    GL16(AP[1] + (AE), &sA[(1 * 1024 + tid) * 8]);                          \
    GL16(wp[0] + (WE), &sB[(0 * 1024 + tid) * 8]);                          \
    GL16(wp[1] + (WE), &sB[(1 * 1024 + tid) * 8]);                          \
} while (0)

// barrier; 16 ds_read_b128 (imm offsets off adA/adB); 32 MFMA; barrier
#define COMPUTE() do {                                                      \
    __syncthreads();                                                        \
    _Pragma("unroll")                                                       \
    for (int kk = 0; kk < 2; ++kk) {                                        \
        bf16x8 af[4], wf[4];                                                \
        _Pragma("unroll")                                                   \
        for (int i = 0; i < 4; ++i)                                         \
            af[i] = *(const bf16x8*)(adA[kk] + i * 1024);                   \
        _Pragma("unroll")                                                   \
        for (int j = 0; j < 4; ++j)                                         \
            wf[j] = *(const bf16x8*)(adB[kk] + j * 1024);                   \
        _Pragma("unroll")                                                   \
        for (int i = 0; i < 4; ++i)                                         \
            _Pragma("unroll")                                               \
            for (int j = 0; j < 4; ++j)                                     \
                acc[i][j] = __builtin_amdgcn_mfma_f32_16x16x32_bf16(        \
                    af[i], wf[j], acc[i][j], 0, 0, 0);                      \
    }                                                                       \
    __syncthreads();                                                        \
} while (0)

// per-tile element offsets: one K-tile = 64 elements (128 B) along K
#define XT(n)  do { STAGE4(xp, (n) * 64, (n) * 64); COMPUTE(); } while (0)
#define HT1(n) do { STAGE4(hp, (n) * 64, (5 + (n)) * 64); COMPUTE(); } while (0)
#define HT2(n) do { STAGE4(hp, (n) * 64, (n) * 64); COMPUTE(); } while (0)

// NTH1: L1 h-region tiles (0 or 8). NTL2: L2 tiles (8 or 16).
// ZM: 0 = merged z=2 (both roles), 1 = L1-only, 2 = L2-only.
template<int NTH1, int NTL2, int ZM>
__global__ __launch_bounds__(1024, 4) void gemm_lstm(
        int t,
        const bf16* __restrict__ W2Vt, const int* __restrict__ sent,
        const bf16* __restrict__ Asrc,   // A2[cur] panel, ld = K2
        bf16* __restrict__ hdst,         // A2[prv], ld = K2; offh by role
        const bf16* __restrict__ Wc1, const bf16* __restrict__ Wc2,
        const float* __restrict__ Bp1, const float* __restrict__ Bp2,
        float* __restrict__ cst1, float* __restrict__ cst2,
        float* __restrict__ outf, int en_out, int cz1, int cz2) {
    // 64 KB: sA [256][64] + sB [256][64]; sA..sB region reused as h xpose buf
    __shared__ __attribute__((aligned(16))) bf16 sh[32768];
    bf16* sA = sh;
    bf16* sB = sh + 16384;

    const int tid  = threadIdx.x;
    const int lane = tid & 63;
    const int wave = tid >> 6;             // 0..15
    const int wm   = wave >> 2, wn = wave & 3;   // 4x4 wave grid

    // XCD-chunked bijective swizzle (nwg%8==0): each XCD gets a contiguous
    // logical chunk, bn-fastest inside => same-bm adjacency is XCD-local.
    int role, rem;
    if (ZM == 0) {
        const int raw = blockIdx.x + (blockIdx.y << 3) + blockIdx.z * 400;
        const int lgc = (raw & 7) * 100 + (raw >> 3);
        role = (lgc >= 400) ? 1 : 0;
        rem  = lgc - (role ? 400 : 0);
    } else {
        const int raw = blockIdx.x + (blockIdx.y << 3);
        rem  = (raw & 7) * 50 + (raw >> 3);
        role = (ZM == 1) ? 1 : 0;
    }
    const int bn = rem & 7;                // gate-col block (fastest), 0..7
    const int bm = rem >> 3;               // row block, 0..49

    // wave-uniform role plumbing
    const bf16*  W;  int ldw, offh, czero;
    const float* Bp; float* cst;
    if (role) { W = Wc1; ldw = K1; offh = 0;   Bp = Bp1; cst = cst1; czero = cz1; }
    else      { W = Wc2; ldw = K2; offh = RNN; Bp = Bp2; cst = cst2; czero = cz2; }

    f32x4 acc[4][4];
#pragma unroll
    for (int i = 0; i < 4; ++i)
#pragma unroll
        for (int j = 0; j < 4; ++j)
#pragma unroll
            for (int rr = 0; rr < 4; ++rr) acc[i][j][rr] = 0.f;

    const int r = lane & 15, q = lane >> 4;

    // staging geometry: chunk ch = c*1024+tid (0..2047); row = ch>>3 (0..255);
    // global k-chunk = (ch&7)^(row&7)  (XOR swizzle, zero bank conflicts)
    int srow[2], scol[2];
#pragma unroll
    for (int c = 0; c < 2; ++c) {
        int ch = c * 1024 + tid;
        srow[c] = ch >> 3;
        scol[c] = ((ch & 7) ^ (srow[c] & 7)) * 8;
    }

    // LDS fragment read bases (per kk): all frag reads are +2048*i byte lits
    // row of A-frag i = wm*64 + i*16 + r -> row&7 == r&7 (64,16 ≡ 0 mod 8)
    const bf16* adA[2];
    const bf16* adB[2];
#pragma unroll
    for (int kk = 0; kk < 2; ++kk) {
        int x = ((q + 4 * kk) ^ (r & 7)) * 8;
        adA[kk] = &sA[(wm * 64 + r) * 64 + x];
        adB[kk] = &sB[(wn * 64 + r) * 64 + x];
    }

    // W staging pointers (fixed; K-advance is the literal WE)
    const bf16* wp[2];
#pragma unroll
    for (int c = 0; c < 2; ++c)
        wp[c] = W + (size_t)(bn * BN + srow[c]) * ldw + scol[c];

    if (ZM == 1 || (ZM == 0 && role)) {
        // ---- L1 role: x-phase (5 tiles, W2Vt gather) then h-phase ----
        {
            const bf16* xp[2];
#pragma unroll
            for (int c = 0; c < 2; ++c) {
                int id = sent[(bm * BM + srow[c]) * TSTEPS + t];  // 8-lane bcast
                xp[c] = W2Vt + (size_t)id * EMBP + scol[c];
            }
            XT(0); XT(1); XT(2); XT(3); XT(4);
        }
        if (NTH1 > 0) {
            const bf16* hp[2];
#pragma unroll
            for (int c = 0; c < 2; ++c)
                hp[c] = Asrc + (size_t)(bm * BM + srow[c]) * K2 + scol[c];
            HT1(0); HT1(1); HT1(2); HT1(3); HT1(4); HT1(5); HT1(6); HT1(7);
        }
    } else {
        // ---- L2 role: 8 or 16 tiles straight from A2[cur] ----
        const bf16* hp[2];
#pragma unroll
        for (int c = 0; c < 2; ++c)
            hp[c] = Asrc + (size_t)(bm * BM + srow[c]) * K2 + scol[c];
        HT2(0); HT2(1); HT2(2); HT2(3); HT2(4); HT2(5); HT2(6); HT2(7);
        if (NTL2 == 16) {
            HT2(8); HT2(9); HT2(10); HT2(11); HT2(12); HT2(13); HT2(14); HT2(15);
        }
    }
    // trailing barrier (inside COMPUTE): sh reads done -> reuse as h buffer

    // ---- fused LSTM epilogue ----
    // C/D mapping (m89/m91-verified): col = lane&15, row = (lane>>4)*4 + reg
    const int colb = bn * BN + wn * 64;
    const int u    = bn * 64 + wn * 16 + r;       // global unit index 0..511
    const float bi = Bp[colb + r];
    const float bf = Bp[colb + 16 + r];
    const float bg = Bp[colb + 32 + r];
    const float bo = Bp[colb + 48 + r];

    // hoist the 16 c-loads so their latency overlaps the math below
    // (czero: first use of this role's c-state -> constant 0, no load)
    float cc[4][4];
    if (czero) {
#pragma unroll
        for (int i = 0; i < 4; ++i)
#pragma unroll
            for (int rr = 0; rr < 4; ++rr) cc[i][rr] = 0.f;
    } else {
#pragma unroll
        for (int i = 0; i < 4; ++i)
#pragma unroll
            for (int rr = 0; rr < 4; ++rr) {
                int row = bm * BM + wm * 64 + i * 16 + q * 4 + rr;
                cc[i][rr] = cst[(size_t)row * RNN + u];
            }
    }

#define HLD 72   // h-xpose row stride: 144B rows (16B-aligned); 256x72x2B=36KB<=64KB
#pragma unroll
    for (int i = 0; i < 4; ++i) {
#pragma unroll
        for (int rr = 0; rr < 4; ++rr) {
            int rowl = wm * 64 + i * 16 + q * 4 + rr;       // row in block 0..255
            int row  = bm * BM + rowl;
            size_t cidx = (size_t)row * RNN + u;
            float gi = acc[i][0][rr] + bi;
            float gf = acc[i][1][rr] + bf;
            float gg = acc[i][2][rr] + bg;
            float go = acc[i][3][rr] + bo;
            float cn = sigmoidf_(gf) * cc[i][rr] + sigmoidf_(gi) * tanhf_(gg);
            float h  = sigmoidf_(go) * tanhf_(cn);
            cst[cidx] = cn;                                  // 64B segments
            if (en_out) outf[cidx] = h;
            sh[rowl * HLD + wn * 16 + r] = __float2bfloat16(h);
        }
    }
    __syncthreads();

    // coalesced h stores: 256 rows x 64 units bf16; 16B x 2048 chunks
#pragma unroll
    for (int hh = 0; hh < 2; ++hh) {
        int t2   = hh * 1024 + tid;        // 0..2047
        int rowl = t2 >> 3;                // 0..255
        int c8   = (t2 & 7) * 8;           // 0..56
        uint4 v  = *(const uint4*)&sh[rowl * HLD + c8];
        int row  = bm * BM + rowl;
        int gcol = bn * 64 + c8;           // unit col within [0,512)
        *(uint4*)&hdst[(size_t)row * K2 + offh + gcol] = v;
    }
#undef HLD
}

// ---------------------------------------------------------------------------
// Workspace layout (all 16B-aligned; total 125,276,160 B):
//   c1   fp32 [12800][512]           26,214,400   offset 0
//   c2   fp32 [12800][512]           26,214,400   offset  26,214,400
//   A2a  bf16 [12800][1024]          26,214,400   offset  52,428,800
//   A2b  bf16 [12800][1024]          26,214,400   offset  78,643,200
//   W2Vt bf16 [20000][320]           12,800,000   offset 104,857,600
//   Wc1  bf16 [2048][832]             3,407,872   offset 117,657,600
//   Wc2  bf16 [2048][1024]            4,194,304   offset 121,065,472
//   Bp1  fp32 [2048]                      8,192   offset 125,259,776
//   Bp2  fp32 [2048]                      8,192   offset 125,267,968
// NO memset: c-state first use is czero-substituted (stage0 L1, s==1 L2);
// A2 needs no init (t=0 tile-count truncation skips the h K-region).
//
// Dispatch schedule (9 GEMM dispatches; cur(t)=t&1):
//   stage 0:      L1(0) alone        gemm_lstm<0,0,1>, cz1
//   stage 1:      [L2(0) || L1(1)]   gemm_lstm<8,8,0>, cz2 (L2 h1-only)
//   stage s=2..7: [L2(s-1) || L1(s)] gemm_lstm<8,16,0>
//       Asrc=A2[(s-1)&1]: L2 reads cols[0,1024), L1 reads cols[0,512) (RR ok)
//       hdst=A2[s&1]:     L2 writes cols[512,1024), L1 writes cols[0,512)
//       => disjoint writes, no read/write overlap: RACE-FREE.
//   stage 8:      L2(7) alone        gemm_lstm<0,16,2>, en_out
// ---------------------------------------------------------------------------
extern "C" void kernel_launch(void* const* d_in, const int* in_sizes, int n_in,
                              void* d_out, int out_size, void* d_ws, size_t ws_size,
                              hipStream_t stream) {
    (void)in_sizes; (void)n_in; (void)out_size; (void)ws_size;
    const int*   sent = (const int*)d_in[0];
    const float* w2v  = (const float*)d_in[1];
    const float* Wih1 = (const float*)d_in[2];
    const float* Whh1 = (const float*)d_in[3];
    const float* bih1 = (const float*)d_in[4];
    const float* bhh1 = (const float*)d_in[5];
    const float* Wih2 = (const float*)d_in[6];
    const float* Whh2 = (const float*)d_in[7];
    const float* bih2 = (const float*)d_in[8];
    const float* bhh2 = (const float*)d_in[9];
    float* out = (float*)d_out;

    char* ws = (char*)d_ws;
    float* c1   = (float*)(ws);
    float* c2   = (float*)(ws + 26214400);
    bf16*  A2[2];
    A2[0] = (bf16*)(ws + 52428800);
    A2[1] = (bf16*)(ws + 78643200);
    bf16*  W2Vt = (bf16*) (ws + 104857600);
    bf16*  Wc1  = (bf16*) (ws + 117657600);
    bf16*  Wc2  = (bf16*) (ws + 121065472);
    float* Bp1  = (float*)(ws + 125259776);
    float* Bp2  = (float*)(ws + 125267968);

    convert_weights<<<dim3((NG * K2 + 255) / 256), dim3(256), 0, stream>>>(
        Wih1, Whh1, Wih2, Whh2, bih1, bhh1, bih2, bhh2, Wc1, Wc2, Bp1, Bp2);

    // one-time pre-tanh'd embedding table
    tanh_w2v<<<dim3(VOCAB), dim3(EMBP), 0, stream>>>(w2v, W2Vt);

    const dim3 blk(1024);
    const dim3 g1(NG / BN, BROWS / BM, 1);   // (8, 50, 1)
    const dim3 g2(NG / BN, BROWS / BM, 2);   // (8, 50, 2)

    // stage 0: L1(0) alone, x-region only (h1(-1)=0, c1(-1)=0)
    gemm_lstm<0, 0, 1><<<g1, blk, 0, stream>>>(
        0, W2Vt, sent, A2[1] /*unused*/, A2[0],
        Wc1, Wc2, Bp1, Bp2, c1, c2,
        (float*)nullptr, 0, 1 /*cz1*/, 0);

    // stage 1: [L2(0) || L1(1)]; L2 truncated to h1-region (h2(-1)=0, c2=0)
    gemm_lstm<8, 8, 0><<<g2, blk, 0, stream>>>(
        1, W2Vt, sent, A2[0], A2[1],
        Wc1, Wc2, Bp1, Bp2, c1, c2,
        (float*)nullptr, 0, 0, 1 /*cz2*/);

    // stages 2..7: merged [L2(s-1) || L1(s)]
    for (int s = 2; s <= 7; ++s) {
        gemm_lstm<8, 16, 0><<<g2, blk, 0, stream>>>(
            s, W2Vt, sent, A2[(s - 1) & 1], A2[s & 1],
            Wc1, Wc2, Bp1, Bp2, c1, c2,
            (float*)nullptr, 0, 0, 0);
    }

    // stage 8: L2(7) alone, writes final h2 -> out (fp32)
    gemm_lstm<0, 16, 2><<<g1, blk, 0, stream>>>(
        0, W2Vt, sent, A2[1], A2[0],
        Wc1, Wc2, Bp1, Bp2, c1, c2,
        out, 1, 0, 0);
}